// Round 8
// baseline (393.394 us; speedup 1.0000x reference)
//
#include <hip/hip_runtime.h>
#include <hip/hip_bf16.h>
#include <cstdint>

#define D_MODEL 2048
#define D_REC   384
#define NPROJ   1152          // 3*D_REC
#define BATCH   4
#define SEQ     4096
#define M_TOTAL (BATCH*SEQ)   // 16384
#define CHUNK   64
#define NCHUNK  (SEQ/CHUNK)   // 64

// GEMM v8: 128x288 tile, grid 128x4 = 512 blocks = 2/CU co-resident.
// A consumed DIRECTLY from global f32 (per-lane fragment loads + in-reg cvt):
// no A-LDS, no staging cvt kernel.  B via v6-verified gload_lds path.
#define BM 128
#define BN 288
#define HK 32                 // K step
#define HT (D_MODEL/HK)       // 64 tiles

typedef __attribute__((ext_vector_type(8))) short  short8;
typedef __attribute__((ext_vector_type(4))) float  f32x4;

__device__ __forceinline__ float rcpf(float x) { return __builtin_amdgcn_rcpf(x); }

__device__ __forceinline__ uint16_t f2bf(float x) {
    __hip_bfloat16 h = __float2bfloat16(x);
    return *reinterpret_cast<uint16_t*>(&h);
}

// ---------------------------------------------------------------- convert W only (9.4 MB)
__global__ void cvt_w(const float* __restrict__ W, uint16_t* __restrict__ Wb) {
    long i = ((long)blockIdx.x * blockDim.x + threadIdx.x) * 4;
    float4 f = *reinterpret_cast<const float4*>(W + i);
    ushort4 o;
    o.x = f2bf(f.x); o.y = f2bf(f.y); o.z = f2bf(f.z); o.w = f2bf(f.w);
    *reinterpret_cast<ushort4*>(Wb + i) = o;
}

// ---------------------------------------------------------------- GEMM v8
// C^T[n][m] = sum_k A[m][k]*B[n][k].  4 waves (2M x 2N), per-wave 64x144.
// A-fragment for 16x16x32 MFMA is A[row][k0+qq*8..+7] (consecutive) -> load
// straight from global as 2x float4 per mt (16 rows x 128B coalesced segs),
// cvt to bf16 at phase top.  B: double-buffered LDS via swizzled gload_lds
// (v6-verified).  Per phase: cvt A(h) -> issue A(h+1)+B(h+1) -> ds_read B
// frags -> 36 MFMA -> __syncthreads (drains h+1 loads under next barrier).
__device__ __forceinline__ void gload_lds16(const uint16_t* g, uint16_t* l) {
    __builtin_amdgcn_global_load_lds(
        (__attribute__((address_space(1))) void*)g,
        (__attribute__((address_space(3))) void*)l,
        16, 0, 0);
}

__launch_bounds__(256, 2)
__global__ void gemm_f32a_v8(const float* __restrict__ Af,    // x [16384][2048] f32
                             const uint16_t* __restrict__ Bm, // W [1152][2048] bf16
                             float* __restrict__ C)           // aivT [1152][16384]
{
    __shared__ __align__(16) uint16_t Bs[2][BN * HK];  // 2 x 18 KiB

    const int tid  = threadIdx.x;
    const int wave = tid >> 6;           // 0..3
    const int lane = tid & 63;
    const int m0 = blockIdx.x * BM;
    const int n0 = blockIdx.y * BN;
    const int wm = (wave >> 1) * 64;     // 2 M-waves
    const int wn = (wave & 1) * 144;     // 2 N-waves

    // ---- B staging (identical to v6/v7): 18 calls of 16 rows; waves own 5,5,4,4
    const int rl = lane >> 2;
    const int cg = (lane & 3) ^ ((rl >> 1) & 3);
    const int cb0 = (wave < 2) ? wave * 5 : 10 + (wave - 2) * 4;
    const long bOff = (long)(n0 + cb0 * 16 + rl) * D_MODEL + cg * 8;

    // ---- fragment addressing
    const int lm  = lane & 15;
    const int qq  = lane >> 4;
    const int kch = (qq ^ ((lm >> 1) & 3)) * 8;   // B LDS read (swizzled)

    // ---- A direct-row pointers (one per mt)
    const float* aP0 = Af + (long)(m0 + wm +  0 + lm) * D_MODEL + qq * 8;
    const float* aP1 = Af + (long)(m0 + wm + 16 + lm) * D_MODEL + qq * 8;
    const float* aP2 = Af + (long)(m0 + wm + 32 + lm) * D_MODEL + qq * 8;
    const float* aP3 = Af + (long)(m0 + wm + 48 + lm) * D_MODEL + qq * 8;

    f32x4 acc[4][9];
#pragma unroll
    for (int i = 0; i < 4; ++i)
#pragma unroll
        for (int j = 0; j < 9; ++j) acc[i][j] = (f32x4){0.f, 0.f, 0.f, 0.f};

    auto stageB = [&](int ht, int slot) {
        const long k0 = (long)ht * HK;
        uint16_t* bb = &Bs[slot][(cb0 * 16) * HK];
        gload_lds16(Bm + bOff + k0,                          bb);
        gload_lds16(Bm + bOff + k0 + (long)16 * D_MODEL,     bb + 16 * HK);
        gload_lds16(Bm + bOff + k0 + (long)32 * D_MODEL,     bb + 32 * HK);
        gload_lds16(Bm + bOff + k0 + (long)48 * D_MODEL,     bb + 48 * HK);
        if (wave < 2)
            gload_lds16(Bm + bOff + k0 + (long)64 * D_MODEL, bb + 64 * HK);
    };

    float4 av[8];
    auto loadA = [&](int h) {
        const long k0 = (long)h * HK;
        av[0] = *reinterpret_cast<const float4*>(aP0 + k0);
        av[1] = *reinterpret_cast<const float4*>(aP0 + k0 + 4);
        av[2] = *reinterpret_cast<const float4*>(aP1 + k0);
        av[3] = *reinterpret_cast<const float4*>(aP1 + k0 + 4);
        av[4] = *reinterpret_cast<const float4*>(aP2 + k0);
        av[5] = *reinterpret_cast<const float4*>(aP2 + k0 + 4);
        av[6] = *reinterpret_cast<const float4*>(aP3 + k0);
        av[7] = *reinterpret_cast<const float4*>(aP3 + k0 + 4);
    };

    // ---- prologue: A(0) regs + B(0) LDS
    loadA(0);
    stageB(0, 0);
    __syncthreads();    // drains vmcnt (av + B landed), block-wide visible

    for (int h = 0; h < HT; ++h) {
        const int cur = h & 1;
        const bool pf = (h + 1) < HT;

        // 1. cvt A(h): av -> af (av landed via previous drain)
        short8 af[4];
#pragma unroll
        for (int mt = 0; mt < 4; ++mt) {
            af[mt][0] = (short)f2bf(av[2 * mt].x);
            af[mt][1] = (short)f2bf(av[2 * mt].y);
            af[mt][2] = (short)f2bf(av[2 * mt].z);
            af[mt][3] = (short)f2bf(av[2 * mt].w);
            af[mt][4] = (short)f2bf(av[2 * mt + 1].x);
            af[mt][5] = (short)f2bf(av[2 * mt + 1].y);
            af[mt][6] = (short)f2bf(av[2 * mt + 1].z);
            af[mt][7] = (short)f2bf(av[2 * mt + 1].w);
        }

        // 2. issue next-tile loads (have the whole MFMA phase to land)
        if (pf) {
            loadA(h + 1);            // WAR on av: cvt above already consumed it
            stageB(h + 1, cur ^ 1);
        }

        // 3. B fragments + MFMA (grouped 3 to bound VGPR)
        const uint16_t* bp = &Bs[cur][0];
        __builtin_amdgcn_s_setprio(1);
#pragma unroll
        for (int g = 0; g < 3; ++g) {
            short8 bfr[3];
#pragma unroll
            for (int nt = 0; nt < 3; ++nt)
                bfr[nt] = *reinterpret_cast<const short8*>(
                    &bp[(wn + (g * 3 + nt) * 16 + lm) * HK + kch]);
#pragma unroll
            for (int mt = 0; mt < 4; ++mt)
#pragma unroll
                for (int nt = 0; nt < 3; ++nt)
                    acc[mt][g * 3 + nt] = __builtin_amdgcn_mfma_f32_16x16x32_bf16(
                        af[mt], bfr[nt], acc[mt][g * 3 + nt], 0, 0, 0);
        }
        __builtin_amdgcn_s_setprio(0);

        // 4. drain + barrier: A(h+1) in regs, B(h+1) visible in LDS
        if (pf) __syncthreads();
    }

    // ---- epilogue (transposed): aivT[col][row..row+3] = acc  (one float4/lane)
#pragma unroll
    for (int mt = 0; mt < 4; ++mt) {
#pragma unroll
        for (int nt = 0; nt < 9; ++nt) {
            const int row = m0 + wm + mt * 16 + qq * 4;
            const int col = n0 + wn + nt * 16 + lm;
            float4 o;
            o.x = acc[mt][nt][0]; o.y = acc[mt][nt][1];
            o.z = acc[mt][nt][2]; o.w = acc[mt][nt][3];
            *reinterpret_cast<float4*>(&C[(long)col * M_TOTAL + row]) = o;
        }
    }
}

// ---------------------------------------------------------------- pass 1: chunk stats
// Same scan as the verified intra_scan_T but stores ONLY the per-chunk tail
// (ctd, cfs) -> the 50MB cumdec/cumw intermediates are never materialized.
__global__ void chunk_stats(const float* __restrict__ aivT, const float* __restrict__ bias,
                            float* __restrict__ ctd,     // [B][NCHUNK][D]
                            float* __restrict__ cfs)     // [B][NCHUNK][D]
{
    const int w = threadIdx.x >> 6;
    const int t = threadIdx.x & 63;
    const int d = blockIdx.z * 4 + w;
    const int c = blockIdx.x;
    const int b = blockIdx.y;
    const long m = (long)b * SEQ + (long)c * CHUNK + t;

    const float ap = aivT[(long)d * M_TOTAL + m];
    const float ip = aivT[(long)(D_REC + d) * M_TOTAL + m];
    const float vv = aivT[(long)(2 * D_REC + d) * M_TOTAL + m];

    const float a   = rcpf(1.f + __expf(-(ap + bias[d])));
    const float g   = rcpf(1.f + __expf(-ip));
    const float sig = sqrtf(fmaxf(1.f - a * a, 1e-8f)) * (g * vv);

    float cd = fmaxf(a, 1e-10f);
#pragma unroll
    for (int off = 1; off < 64; off <<= 1) {
        const float o = __shfl_up(cd, off, 64);
        cd = (t >= off) ? cd * o : cd;
    }
    float cw = sig * rcpf(fmaxf(cd, 1e-10f));
#pragma unroll
    for (int off = 1; off < 64; off <<= 1) {
        const float o = __shfl_up(cw, off, 64);
        cw = (t >= off) ? cw + o : cw;
    }

    if (t == 63) {
        const long cb = ((long)b * NCHUNK + c) * D_REC + d;
        ctd[cb] = cd;
        cfs[cb] = cd * cw;
    }
}

// ---------------------------------------------------------------- cross-chunk scan
__global__ void cross_scan(const float* __restrict__ ctd, const float* __restrict__ cfs,
                           float* __restrict__ incoming)  // [B][NCHUNK][D]
{
    const int d = threadIdx.x;
    const int b = blockIdx.x;
    float cdk = 1.f, cwk = 0.f;
    incoming[(long)b * NCHUNK * D_REC + d] = 0.f;
#pragma unroll 4
    for (int c = 0; c < NCHUNK; ++c) {
        const long idx = ((long)b * NCHUNK + c) * D_REC + d;
        const float td = ctd[idx];
        const float fs = cfs[idx];
        cdk *= fmaxf(td, 1e-10f);
        cwk += fs * rcpf(fmaxf(cdk, 1e-10f));
        if (c + 1 < NCHUNK) incoming[idx + D_REC] = cdk * cwk;
    }
}

// ---------------------------------------------------------------- pass 2: recompute + combine
// Recomputes gates+scans (aivT is L3-resident), applies incoming, writes out
// [B][S][D] coalesced via a padded LDS transpose (64 rows x 16 d = full 64B
// line per 4 threads).  Block 256 = 4 waves; wave w covers d = d0 + w*4 + i.
__global__ void scan_combine_T(const float* __restrict__ aivT, const float* __restrict__ bias,
                               const float* __restrict__ inc, float* __restrict__ out)
{
    __shared__ float tile[64][17];
    const int w = threadIdx.x >> 6;
    const int t = threadIdx.x & 63;
    const int c = blockIdx.x;
    const int b = blockIdx.y;
    const int d0 = blockIdx.z * 16;
    const long m = (long)b * SEQ + (long)c * CHUNK + t;

#pragma unroll
    for (int i = 0; i < 4; ++i) {
        const int dd = w * 4 + i;
        const int d  = d0 + dd;

        const float ap = aivT[(long)d * M_TOTAL + m];
        const float ip = aivT[(long)(D_REC + d) * M_TOTAL + m];
        const float vv = aivT[(long)(2 * D_REC + d) * M_TOTAL + m];

        const float a   = rcpf(1.f + __expf(-(ap + bias[d])));
        const float g   = rcpf(1.f + __expf(-ip));
        const float sig = sqrtf(fmaxf(1.f - a * a, 1e-8f)) * (g * vv);

        float cd = fmaxf(a, 1e-10f);
#pragma unroll
        for (int off = 1; off < 64; off <<= 1) {
            const float o = __shfl_up(cd, off, 64);
            cd = (t >= off) ? cd * o : cd;
        }
        float cw = sig * rcpf(fmaxf(cd, 1e-10f));
#pragma unroll
        for (int off = 1; off < 64; off <<= 1) {
            const float o = __shfl_up(cw, off, 64);
            cw = (t >= off) ? cw + o : cw;
        }

        const float ic = inc[((long)b * NCHUNK + c) * D_REC + d];
        tile[t][dd] = cd * (cw + ic);
    }
    __syncthreads();

    // transpose write: thread -> (row, 4-d group); 4 threads cover a 64B line
    const int row = threadIdx.x >> 2;
    const int dq  = (threadIdx.x & 3) * 4;
    float4 o;
    o.x = tile[row][dq];     o.y = tile[row][dq + 1];
    o.z = tile[row][dq + 2]; o.w = tile[row][dq + 3];
    *reinterpret_cast<float4*>(
        &out[((long)b * SEQ + (long)c * CHUNK + row) * D_REC + d0 + dq]) = o;
}

// ---------------------------------------------------------------- launch
extern "C" void kernel_launch(void* const* d_in, const int* in_sizes, int n_in,
                              void* d_out, int out_size, void* d_ws, size_t ws_size,
                              hipStream_t stream) {
    const float* x  = (const float*)d_in[0];   // [4][4096][2048]
    const float* W  = (const float*)d_in[1];   // [1152][2048]
    const float* db = (const float*)d_in[2];   // [384]
    float* out = (float*)d_out;                // [4][4096][384]

    char* ws = (char*)d_ws;
    float*    aivT = (float*)   (ws + 0);            // 75,497,472 B  [1152][16384]
    uint16_t* Wb   = (uint16_t*)(ws + 75497472L);    //  4,718,592 B
    float*    ctd  = (float*)   (ws + 80216064L);    //    393,216 B
    float*    cfs  = (float*)   (ws + 80609280L);    //    393,216 B
    float*    inc  = (float*)   (ws + 81002496L);    //    393,216 B

    // 1. convert W only (x is consumed as f32 by the GEMM)
    cvt_w<<<(int)((long)NPROJ * D_MODEL / (4 * 256)), 256, 0, stream>>>(W, Wb);

    // 2. aivT = (x . W^T)^T : bf16 MFMA, A direct-from-global f32
    gemm_f32a_v8<<<dim3(M_TOTAL / BM, NPROJ / BN), 256, 0, stream>>>(x, Wb, aivT);

    // 3. per-chunk tail stats (no bulk intermediates)
    chunk_stats<<<dim3(NCHUNK, BATCH, D_REC / 4), 256, 0, stream>>>(aivT, db, ctd, cfs);

    // 4. cross-chunk scan
    cross_scan<<<BATCH, D_REC, 0, stream>>>(ctd, cfs, inc);

    // 5. recompute + combine + coalesced transpose write
    scan_combine_T<<<dim3(NCHUNK, BATCH, D_REC / 16), 256, 0, stream>>>(aivT, db, inc, out);
}

// Round 9
// 354.317 us; speedup vs baseline: 1.1103x; 1.1103x over previous
//
#include <hip/hip_runtime.h>
#include <hip/hip_bf16.h>
#include <cstdint>

#define D_MODEL 2048
#define D_REC   384
#define NPROJ   1152          // 3*D_REC
#define BATCH   4
#define SEQ     4096
#define M_TOTAL (BATCH*SEQ)   // 16384
#define CHUNK   64
#define NCHUNK  (SEQ/CHUNK)   // 64

// GEMM v6 geometry (harness-verified 86.4us): 128x288 tile, grid 128x4 = 512
// blocks = 2/CU co-resident.
#define BM 128
#define BN 288
#define HK 32                 // half-K step
#define HT (D_MODEL/HK)       // 64 half-tiles

typedef __attribute__((ext_vector_type(8))) short  short8;
typedef __attribute__((ext_vector_type(4))) float  f32x4;

__device__ __forceinline__ float rcpf(float x) { return __builtin_amdgcn_rcpf(x); }

__device__ __forceinline__ uint16_t f2bf(float x) {
    __hip_bfloat16 h = __float2bfloat16(x);
    return *reinterpret_cast<uint16_t*>(&h);
}

// ---------------------------------------------------------------- convert (verified round-3)
__global__ void cvt_both(const float* __restrict__ x, uint16_t* __restrict__ xb,
                         const float* __restrict__ W, uint16_t* __restrict__ Wb) {
    const long nx = (long)M_TOTAL * D_MODEL;
    const long nw = (long)NPROJ * D_MODEL;
    long i = ((long)blockIdx.x * blockDim.x + threadIdx.x) * 4;
    if (i < nx) {
        float4 f = *reinterpret_cast<const float4*>(x + i);
        ushort4 o;
        o.x = f2bf(f.x); o.y = f2bf(f.y); o.z = f2bf(f.z); o.w = f2bf(f.w);
        *reinterpret_cast<ushort4*>(xb + i) = o;
    } else {
        long j = i - nx;
        if (j < nw) {
            float4 f = *reinterpret_cast<const float4*>(W + j);
            ushort4 o;
            o.x = f2bf(f.x); o.y = f2bf(f.y); o.z = f2bf(f.z); o.w = f2bf(f.w);
            *reinterpret_cast<ushort4*>(Wb + j) = o;
        }
    }
}

// ---------------------------------------------------------------- GEMM (byte-identical verified v6)
__device__ __forceinline__ void gload_lds16(const uint16_t* g, uint16_t* l) {
    __builtin_amdgcn_global_load_lds(
        (__attribute__((address_space(1))) void*)g,
        (__attribute__((address_space(3))) void*)l,
        16, 0, 0);
}

__launch_bounds__(256, 2)
__global__ void gemm_bf16nt_v6(const uint16_t* __restrict__ A,   // [16384][2048]
                               const uint16_t* __restrict__ Bm,  // [1152][2048]
                               float* __restrict__ C)            // aivT [1152][16384]
{
    __shared__ __align__(16) uint16_t As[3][BM * HK];  // 3 x 8 KiB
    __shared__ __align__(16) uint16_t Bs[3][BN * HK];  // 3 x 18 KiB

    const int tid  = threadIdx.x;
    const int wave = tid >> 6;           // 0..3
    const int lane = tid & 63;
    const int m0 = blockIdx.x * BM;
    const int n0 = blockIdx.y * BN;
    const int wm = (wave >> 1) * 64;     // 2 M-waves
    const int wn = (wave & 1) * 144;     // 2 N-waves

    // ---- staging addressing: one call = 16 rows x 32 cols (64 lanes x 16B)
    const int rl = lane >> 2;                     // 0..15 row within call
    const int cg = (lane & 3) ^ ((rl >> 1) & 3);  // swizzled 16B chunk (of 4)
    const int cb0 = (wave < 2) ? wave * 5 : 10 + (wave - 2) * 4;
    const long aOff = (long)(m0 + wave * 32 + rl) * D_MODEL + cg * 8;
    const long bOff = (long)(n0 + cb0 * 16 + rl) * D_MODEL + cg * 8;

    // ---- fragment addressing
    const int lm  = lane & 15;
    const int qq  = lane >> 4;
    const int kch = (qq ^ ((lm >> 1) & 3)) * 8;   // lane-constant k-chunk (elems)

    f32x4 acc[4][9];
#pragma unroll
    for (int i = 0; i < 4; ++i)
#pragma unroll
        for (int j = 0; j < 9; ++j) acc[i][j] = (f32x4){0.f, 0.f, 0.f, 0.f};

    auto stage = [&](int ht) {
        const int p = ht % 3;
        const long k0 = (long)ht * HK;
        uint16_t* ab = &As[p][(wave * 32) * HK];
        uint16_t* bb = &Bs[p][(cb0 * 16) * HK];
        gload_lds16(A + aOff + k0,                          ab);
        gload_lds16(A + aOff + k0 + (long)16 * D_MODEL,     ab + 16 * HK);
        gload_lds16(Bm + bOff + k0,                         bb);
        gload_lds16(Bm + bOff + k0 + (long)16 * D_MODEL,    bb + 16 * HK);
        gload_lds16(Bm + bOff + k0 + (long)32 * D_MODEL,    bb + 32 * HK);
        gload_lds16(Bm + bOff + k0 + (long)48 * D_MODEL,    bb + 48 * HK);
        if (wave < 2)
            gload_lds16(Bm + bOff + k0 + (long)64 * D_MODEL, bb + 64 * HK);
    };

    // ---- prologue: fill ring slots 0,1
    stage(0);
    stage(1);

    for (int h = 0; h < HT; ++h) {
        // 1. counted wait: own stage(h) landed; stage(h+1) stays in flight
        if (h < HT - 1) {
            if (wave < 2) asm volatile("s_waitcnt vmcnt(7)" ::: "memory");
            else          asm volatile("s_waitcnt vmcnt(6)" ::: "memory");
        } else {
            asm volatile("s_waitcnt vmcnt(0)" ::: "memory");
        }
        __builtin_amdgcn_sched_barrier(0);
        __builtin_amdgcn_s_barrier();          // A: stage(h) visible block-wide

        // 2. fragment reads from slot h%3
        const uint16_t* ap = &As[h % 3][0];
        const uint16_t* bp = &Bs[h % 3][0];
        short8 af[4], bfr[9];
#pragma unroll
        for (int mt = 0; mt < 4; ++mt)
            af[mt] = *reinterpret_cast<const short8*>(
                &ap[(wm + mt * 16 + lm) * HK + kch]);
#pragma unroll
        for (int nt = 0; nt < 9; ++nt)
            bfr[nt] = *reinterpret_cast<const short8*>(
                &bp[(wn + nt * 16 + lm) * HK + kch]);

        asm volatile("s_waitcnt lgkmcnt(0)" ::: "memory");
        __builtin_amdgcn_sched_barrier(0);
        __builtin_amdgcn_s_barrier();          // B: slot h%3 reads done block-wide
        __builtin_amdgcn_sched_barrier(0);

        // 3. prefetch stage(h+2) -> slot (h+2)%3 (freed by barrier B of h-1)
        if (h + 2 < HT) stage(h + 2);

        // 4. MFMA cluster
        __builtin_amdgcn_s_setprio(1);
#pragma unroll
        for (int mt = 0; mt < 4; ++mt)
#pragma unroll
            for (int nt = 0; nt < 9; ++nt)
                acc[mt][nt] = __builtin_amdgcn_mfma_f32_16x16x32_bf16(
                    af[mt], bfr[nt], acc[mt][nt], 0, 0, 0);
        __builtin_amdgcn_s_setprio(0);
    }

    // ---- epilogue (transposed): aivT[col][row..row+3] = acc  (one float4/lane)
#pragma unroll
    for (int mt = 0; mt < 4; ++mt) {
#pragma unroll
        for (int nt = 0; nt < 9; ++nt) {
            const int row = m0 + wm + mt * 16 + qq * 4;
            const int col = n0 + wn + nt * 16 + lm;
            float4 o;
            o.x = acc[mt][nt][0]; o.y = acc[mt][nt][1];
            o.z = acc[mt][nt][2]; o.w = acc[mt][nt][3];
            *reinterpret_cast<float4*>(&C[(long)col * M_TOTAL + row]) = o;
        }
    }
}

// ---------------------------------------------------------------- fused scan
// ONE kernel = chunk_stats + cross_scan + combine + transpose-out.
// Grid (D_REC/16, BATCH) = 96 blocks, block 512 = 8 waves; wave w owns
// d = d0 + 2w, d0 + 2w + 1; lane = t.  Chunks processed sequentially with
// the cross-chunk state (cdk, cwk per d) carried in registers; per chunk a
// wave-parallel 6-step shfl scan (verified math), then a padded-LDS
// transpose (pad 20 -> 16B-aligned float4, 2-way-free reads) and 64B-line
// coalesced writes of out[b][s][d].  Explicit next-chunk prefetch.
__device__ __forceinline__ float scan_step(float ap, float ip, float vv,
                                           float bias_d, int t,
                                           float& cdk, float& cwk)
{
    const float a   = rcpf(1.f + __expf(-(ap + bias_d)));
    const float g   = rcpf(1.f + __expf(-ip));
    const float sig = sqrtf(fmaxf(1.f - a * a, 1e-8f)) * (g * vv);

    float cd = fmaxf(a, 1e-10f);
#pragma unroll
    for (int off = 1; off < 64; off <<= 1) {
        const float o = __shfl_up(cd, off, 64);
        cd = (t >= off) ? cd * o : cd;
    }
    float cw = sig * rcpf(fmaxf(cd, 1e-10f));
#pragma unroll
    for (int off = 1; off < 64; off <<= 1) {
        const float o = __shfl_up(cw, off, 64);
        cw = (t >= off) ? cw + o : cw;
    }

    const float res = cd * (cw + cdk * cwk);   // incoming = cdk*cwk (0 at c=0)

    const float td = __shfl(cd, 63, 64);
    const float tw = __shfl(cw, 63, 64);
    cdk *= fmaxf(td, 1e-10f);
    cwk += (td * tw) * rcpf(fmaxf(cdk, 1e-10f));
    return res;
}

__launch_bounds__(512)
__global__ void fused_scan(const float* __restrict__ aivT, const float* __restrict__ bias,
                           float* __restrict__ out)
{
    __shared__ float tile[64][20];   // pad 20: 16B-aligned rows, 2-way-free b128 reads
    const int tid = threadIdx.x;
    const int w = tid >> 6;          // 0..7
    const int t = tid & 63;
    const int d0 = blockIdx.x * 16;
    const int b  = blockIdx.y;
    const int dA = d0 + 2 * w;
    const int dB = dA + 1;
    const float biasA = bias[dA];
    const float biasB = bias[dB];

    const long mb = (long)b * SEQ + t;
    const float* pA0 = aivT + (long)dA * M_TOTAL + mb;                 // a_proj
    const float* pA1 = aivT + (long)(D_REC + dA) * M_TOTAL + mb;       // i_proj
    const float* pA2 = aivT + (long)(2 * D_REC + dA) * M_TOTAL + mb;   // v
    const float* pB0 = aivT + (long)dB * M_TOTAL + mb;
    const float* pB1 = aivT + (long)(D_REC + dB) * M_TOTAL + mb;
    const float* pB2 = aivT + (long)(2 * D_REC + dB) * M_TOTAL + mb;

    float cdkA = 1.f, cwkA = 0.f, cdkB = 1.f, cwkB = 0.f;

    // prefetch chunk 0
    float a0 = pA0[0], a1 = pA1[0], a2 = pA2[0];
    float b0 = pB0[0], b1 = pB1[0], b2 = pB2[0];

    for (int c = 0; c < NCHUNK; ++c) {
        float n0, n1, n2, n3, n4, n5;
        if (c + 1 < NCHUNK) {
            const long o = (long)(c + 1) * CHUNK;
            n0 = pA0[o]; n1 = pA1[o]; n2 = pA2[o];
            n3 = pB0[o]; n4 = pB1[o]; n5 = pB2[o];
        }

        const float resA = scan_step(a0, a1, a2, biasA, t, cdkA, cwkA);
        const float resB = scan_step(b0, b1, b2, biasB, t, cdkB, cwkB);

        tile[t][2 * w]     = resA;
        tile[t][2 * w + 1] = resB;
        __syncthreads();

        if (tid < 256) {
            const int row = tid >> 2;
            const int dq  = (tid & 3) * 4;
            float4 o;
            o.x = tile[row][dq];     o.y = tile[row][dq + 1];
            o.z = tile[row][dq + 2]; o.w = tile[row][dq + 3];
            *reinterpret_cast<float4*>(
                &out[((long)b * SEQ + (long)c * CHUNK + row) * D_REC + d0 + dq]) = o;
        }
        __syncthreads();

        a0 = n0; a1 = n1; a2 = n2;
        b0 = n3; b1 = n4; b2 = n5;
    }
}

// ---------------------------------------------------------------- launch
extern "C" void kernel_launch(void* const* d_in, const int* in_sizes, int n_in,
                              void* d_out, int out_size, void* d_ws, size_t ws_size,
                              hipStream_t stream) {
    const float* x  = (const float*)d_in[0];   // [4][4096][2048]
    const float* W  = (const float*)d_in[1];   // [1152][2048]
    const float* db = (const float*)d_in[2];   // [384]
    float* out = (float*)d_out;                // [4][4096][384]

    char* ws = (char*)d_ws;
    float*    aivT = (float*)   (ws + 0);            // 75,497,472 B  [1152][16384]
    uint16_t* xb   = (uint16_t*)(ws + 75497472L);    // 67,108,864 B
    uint16_t* Wb   = (uint16_t*)(ws + 142606336L);   //  4,718,592 B

    // 1. convert x and W to bf16 (single launch, verified)
    {
        const long ntot = (long)M_TOTAL * D_MODEL + (long)NPROJ * D_MODEL;
        cvt_both<<<(int)((ntot + 1023) / 1024), 256, 0, stream>>>(x, xb, W, Wb);
    }

    // 2. aivT = (x . W^T)^T via bf16 MFMA (verified v6, 86us)
    gemm_bf16nt_v6<<<dim3(M_TOTAL / BM, NPROJ / BN), 256, 0, stream>>>(xb, Wb, aivT);

    // 3. fused intra-scan + cross-scan + combine + transposed write (1 launch)
    fused_scan<<<dim3(D_REC / 16, BATCH), 512, 0, stream>>>(aivT, db, out);
}

// Round 10
// 339.388 us; speedup vs baseline: 1.1591x; 1.0440x over previous
//
#include <hip/hip_runtime.h>
#include <hip/hip_bf16.h>
#include <cstdint>

#define D_MODEL 2048
#define D_REC   384
#define NPROJ   1152          // 3*D_REC
#define BATCH   4
#define SEQ     4096
#define M_TOTAL (BATCH*SEQ)   // 16384
#define CHUNK   64
#define NCHUNK  (SEQ/CHUNK)   // 64

// GEMM v6 geometry (harness-verified 83-86us): 128x288 tile, grid 128x4 = 512
// blocks = 2/CU co-resident.
#define BM 128
#define BN 288
#define HK 32                 // half-K step
#define HT (D_MODEL/HK)       // 64 half-tiles

typedef __attribute__((ext_vector_type(8))) short  short8;
typedef __attribute__((ext_vector_type(4))) float  f32x4;

__device__ __forceinline__ float rcpf(float x) { return __builtin_amdgcn_rcpf(x); }

__device__ __forceinline__ uint16_t f2bf(float x) {
    __hip_bfloat16 h = __float2bfloat16(x);
    return *reinterpret_cast<uint16_t*>(&h);
}

// ---------------------------------------------------------------- convert (verified)
__global__ void cvt_both(const float* __restrict__ x, uint16_t* __restrict__ xb,
                         const float* __restrict__ W, uint16_t* __restrict__ Wb) {
    const long nx = (long)M_TOTAL * D_MODEL;
    const long nw = (long)NPROJ * D_MODEL;
    long i = ((long)blockIdx.x * blockDim.x + threadIdx.x) * 4;
    if (i < nx) {
        float4 f = *reinterpret_cast<const float4*>(x + i);
        ushort4 o;
        o.x = f2bf(f.x); o.y = f2bf(f.y); o.z = f2bf(f.z); o.w = f2bf(f.w);
        *reinterpret_cast<ushort4*>(xb + i) = o;
    } else {
        long j = i - nx;
        if (j < nw) {
            float4 f = *reinterpret_cast<const float4*>(W + j);
            ushort4 o;
            o.x = f2bf(f.x); o.y = f2bf(f.y); o.z = f2bf(f.z); o.w = f2bf(f.w);
            *reinterpret_cast<ushort4*>(Wb + j) = o;
        }
    }
}

// ---------------------------------------------------------------- GEMM (byte-identical verified v6)
__device__ __forceinline__ void gload_lds16(const uint16_t* g, uint16_t* l) {
    __builtin_amdgcn_global_load_lds(
        (__attribute__((address_space(1))) void*)g,
        (__attribute__((address_space(3))) void*)l,
        16, 0, 0);
}

__launch_bounds__(256, 2)
__global__ void gemm_bf16nt_v6(const uint16_t* __restrict__ A,   // [16384][2048]
                               const uint16_t* __restrict__ Bm,  // [1152][2048]
                               float* __restrict__ C)            // aivT [1152][16384]
{
    __shared__ __align__(16) uint16_t As[3][BM * HK];  // 3 x 8 KiB
    __shared__ __align__(16) uint16_t Bs[3][BN * HK];  // 3 x 18 KiB

    const int tid  = threadIdx.x;
    const int wave = tid >> 6;           // 0..3
    const int lane = tid & 63;
    const int m0 = blockIdx.x * BM;
    const int n0 = blockIdx.y * BN;
    const int wm = (wave >> 1) * 64;     // 2 M-waves
    const int wn = (wave & 1) * 144;     // 2 N-waves

    const int rl = lane >> 2;                     // 0..15 row within call
    const int cg = (lane & 3) ^ ((rl >> 1) & 3);  // swizzled 16B chunk (of 4)
    const int cb0 = (wave < 2) ? wave * 5 : 10 + (wave - 2) * 4;
    const long aOff = (long)(m0 + wave * 32 + rl) * D_MODEL + cg * 8;
    const long bOff = (long)(n0 + cb0 * 16 + rl) * D_MODEL + cg * 8;

    const int lm  = lane & 15;
    const int qq  = lane >> 4;
    const int kch = (qq ^ ((lm >> 1) & 3)) * 8;

    f32x4 acc[4][9];
#pragma unroll
    for (int i = 0; i < 4; ++i)
#pragma unroll
        for (int j = 0; j < 9; ++j) acc[i][j] = (f32x4){0.f, 0.f, 0.f, 0.f};

    auto stage = [&](int ht) {
        const int p = ht % 3;
        const long k0 = (long)ht * HK;
        uint16_t* ab = &As[p][(wave * 32) * HK];
        uint16_t* bb = &Bs[p][(cb0 * 16) * HK];
        gload_lds16(A + aOff + k0,                          ab);
        gload_lds16(A + aOff + k0 + (long)16 * D_MODEL,     ab + 16 * HK);
        gload_lds16(Bm + bOff + k0,                         bb);
        gload_lds16(Bm + bOff + k0 + (long)16 * D_MODEL,    bb + 16 * HK);
        gload_lds16(Bm + bOff + k0 + (long)32 * D_MODEL,    bb + 32 * HK);
        gload_lds16(Bm + bOff + k0 + (long)48 * D_MODEL,    bb + 48 * HK);
        if (wave < 2)
            gload_lds16(Bm + bOff + k0 + (long)64 * D_MODEL, bb + 64 * HK);
    };

    stage(0);
    stage(1);

    for (int h = 0; h < HT; ++h) {
        if (h < HT - 1) {
            if (wave < 2) asm volatile("s_waitcnt vmcnt(7)" ::: "memory");
            else          asm volatile("s_waitcnt vmcnt(6)" ::: "memory");
        } else {
            asm volatile("s_waitcnt vmcnt(0)" ::: "memory");
        }
        __builtin_amdgcn_sched_barrier(0);
        __builtin_amdgcn_s_barrier();          // A: stage(h) visible block-wide

        const uint16_t* ap = &As[h % 3][0];
        const uint16_t* bp = &Bs[h % 3][0];
        short8 af[4], bfr[9];
#pragma unroll
        for (int mt = 0; mt < 4; ++mt)
            af[mt] = *reinterpret_cast<const short8*>(
                &ap[(wm + mt * 16 + lm) * HK + kch]);
#pragma unroll
        for (int nt = 0; nt < 9; ++nt)
            bfr[nt] = *reinterpret_cast<const short8*>(
                &bp[(wn + nt * 16 + lm) * HK + kch]);

        asm volatile("s_waitcnt lgkmcnt(0)" ::: "memory");
        __builtin_amdgcn_sched_barrier(0);
        __builtin_amdgcn_s_barrier();          // B: slot h%3 reads done block-wide
        __builtin_amdgcn_sched_barrier(0);

        if (h + 2 < HT) stage(h + 2);

        __builtin_amdgcn_s_setprio(1);
#pragma unroll
        for (int mt = 0; mt < 4; ++mt)
#pragma unroll
            for (int nt = 0; nt < 9; ++nt)
                acc[mt][nt] = __builtin_amdgcn_mfma_f32_16x16x32_bf16(
                    af[mt], bfr[nt], acc[mt][nt], 0, 0, 0);
        __builtin_amdgcn_s_setprio(0);
    }

#pragma unroll
    for (int mt = 0; mt < 4; ++mt) {
#pragma unroll
        for (int nt = 0; nt < 9; ++nt) {
            const int row = m0 + wm + mt * 16 + qq * 4;
            const int col = n0 + wn + nt * 16 + lm;
            float4 o;
            o.x = acc[mt][nt][0]; o.y = acc[mt][nt][1];
            o.z = acc[mt][nt][2]; o.w = acc[mt][nt][3];
            *reinterpret_cast<float4*>(&C[(long)col * M_TOTAL + row]) = o;
        }
    }
}

// ---------------------------------------------------------------- pass 1: chunk tails
// Verified chunk_stats math; tails stored CHUNK-MAJOR [b][d][c] so pass 2 can
// lane-load them coalesced (lane = chunk).
__global__ void chunk_tails(const float* __restrict__ aivT, const float* __restrict__ bias,
                            float* __restrict__ ctdT,    // [B][D_REC][NCHUNK]
                            float* __restrict__ cfsT)    // [B][D_REC][NCHUNK]
{
    const int w = threadIdx.x >> 6;
    const int t = threadIdx.x & 63;
    const int d = blockIdx.z * 4 + w;
    const int c = blockIdx.x;
    const int b = blockIdx.y;
    const long m = (long)b * SEQ + (long)c * CHUNK + t;

    const float ap = aivT[(long)d * M_TOTAL + m];
    const float ip = aivT[(long)(D_REC + d) * M_TOTAL + m];
    const float vv = aivT[(long)(2 * D_REC + d) * M_TOTAL + m];

    const float a   = rcpf(1.f + __expf(-(ap + bias[d])));
    const float g   = rcpf(1.f + __expf(-ip));
    const float sig = sqrtf(fmaxf(1.f - a * a, 1e-8f)) * (g * vv);

    float cd = fmaxf(a, 1e-10f);
#pragma unroll
    for (int off = 1; off < 64; off <<= 1) {
        const float o = __shfl_up(cd, off, 64);
        cd = (t >= off) ? cd * o : cd;
    }
    float cw = sig * rcpf(fmaxf(cd, 1e-10f));
#pragma unroll
    for (int off = 1; off < 64; off <<= 1) {
        const float o = __shfl_up(cw, off, 64);
        cw = (t >= off) ? cw + o : cw;
    }

    if (t == 63) {
        const long idx = ((long)b * D_REC + d) * NCHUNK + c;
        ctdT[idx] = cd;
        cfsT[idx] = cd * cw;
    }
}

// ---------------------------------------------------------------- pass 2: apply
// Grid (NCHUNK, BATCH, D_REC/16), block 1024 = 16 waves; wave w owns d = d0+w,
// lane = t.  Each wave first recomputes the cross-chunk prefix IN-REGISTER
// (lane j = chunk j): P = prefix-prod of clipped tails, S = prefix-sum of
// fs/clip(P) -- exactly the verified cross_scan recurrence -- then takes lane
// c-1's P*S as the incoming state, runs the verified intra scan for chunk c,
// and writes out[b][s][d] through a padded-LDS transpose (64B lines).
__launch_bounds__(1024)
__global__ void scan_apply(const float* __restrict__ aivT, const float* __restrict__ bias,
                           const float* __restrict__ ctdT, const float* __restrict__ cfsT,
                           float* __restrict__ out)
{
    __shared__ float tile[64][17];
    const int w = threadIdx.x >> 6;          // 0..15
    const int t = threadIdx.x & 63;
    const int c = blockIdx.x;
    const int b = blockIdx.y;
    const int d0 = blockIdx.z * 16;
    const int d = d0 + w;

    // ---- incoming state via lane-parallel tail scan (lane = chunk)
    float inc = 0.f;
    {
        const long tb = ((long)b * D_REC + d) * NCHUNK;
        const float td = ctdT[tb + t];
        const float fs = cfsT[tb + t];
        float P = fmaxf(td, 1e-10f);
#pragma unroll
        for (int off = 1; off < 64; off <<= 1) {
            const float o = __shfl_up(P, off, 64);
            P = (t >= off) ? P * o : P;
        }
        float S = fs * rcpf(fmaxf(P, 1e-10f));
#pragma unroll
        for (int off = 1; off < 64; off <<= 1) {
            const float o = __shfl_up(S, off, 64);
            S = (t >= off) ? S + o : S;
        }
        const float R = P * S;
        if (c > 0) inc = __shfl(R, c - 1, 64);
    }

    // ---- own chunk intra scan (verified math)
    const long m = (long)b * SEQ + (long)c * CHUNK + t;
    const float ap = aivT[(long)d * M_TOTAL + m];
    const float ip = aivT[(long)(D_REC + d) * M_TOTAL + m];
    const float vv = aivT[(long)(2 * D_REC + d) * M_TOTAL + m];

    const float a   = rcpf(1.f + __expf(-(ap + bias[d])));
    const float g   = rcpf(1.f + __expf(-ip));
    const float sig = sqrtf(fmaxf(1.f - a * a, 1e-8f)) * (g * vv);

    float cd = fmaxf(a, 1e-10f);
#pragma unroll
    for (int off = 1; off < 64; off <<= 1) {
        const float o = __shfl_up(cd, off, 64);
        cd = (t >= off) ? cd * o : cd;
    }
    float cw = sig * rcpf(fmaxf(cd, 1e-10f));
#pragma unroll
    for (int off = 1; off < 64; off <<= 1) {
        const float o = __shfl_up(cw, off, 64);
        cw = (t >= off) ? cw + o : cw;
    }

    tile[t][w] = cd * (cw + inc);
    __syncthreads();

    // ---- transposed write: 256 threads cover 64 rows x 4 float4 = 64B lines
    if (threadIdx.x < 256) {
        const int row = threadIdx.x >> 2;
        const int dq  = (threadIdx.x & 3) * 4;
        float4 o;
        o.x = tile[row][dq];     o.y = tile[row][dq + 1];
        o.z = tile[row][dq + 2]; o.w = tile[row][dq + 3];
        *reinterpret_cast<float4*>(
            &out[((long)b * SEQ + (long)c * CHUNK + row) * D_REC + d0 + dq]) = o;
    }
}

// ---------------------------------------------------------------- launch
extern "C" void kernel_launch(void* const* d_in, const int* in_sizes, int n_in,
                              void* d_out, int out_size, void* d_ws, size_t ws_size,
                              hipStream_t stream) {
    const float* x  = (const float*)d_in[0];   // [4][4096][2048]
    const float* W  = (const float*)d_in[1];   // [1152][2048]
    const float* db = (const float*)d_in[2];   // [384]
    float* out = (float*)d_out;                // [4][4096][384]

    char* ws = (char*)d_ws;
    float*    aivT = (float*)   (ws + 0);            // 75,497,472 B  [1152][16384]
    uint16_t* xb   = (uint16_t*)(ws + 75497472L);    // 67,108,864 B
    uint16_t* Wb   = (uint16_t*)(ws + 142606336L);   //  4,718,592 B
    float*    ctdT = (float*)   (ws + 147324928L);   //    393,216 B  [4][384][64]
    float*    cfsT = (float*)   (ws + 147718144L);   //    393,216 B

    // 1. convert x and W to bf16 (verified)
    {
        const long ntot = (long)M_TOTAL * D_MODEL + (long)NPROJ * D_MODEL;
        cvt_both<<<(int)((ntot + 1023) / 1024), 256, 0, stream>>>(x, xb, W, Wb);
    }

    // 2. aivT = (x . W^T)^T via bf16 MFMA (verified v6, 83us)
    gemm_bf16nt_v6<<<dim3(M_TOTAL / BM, NPROJ / BN), 256, 0, stream>>>(xb, Wb, aivT);

    // 3. per-chunk tails, chunk-major layout (fully parallel)
    chunk_tails<<<dim3(NCHUNK, BATCH, D_REC / 4), 256, 0, stream>>>(aivT, db, ctdT, cfsT);

    // 4. in-register cross prefix + intra scan + combine + transposed write
    scan_apply<<<dim3(NCHUNK, BATCH, D_REC / 16), 1024, 0, stream>>>(aivT, db, ctdT, cfsT, out);
}